// Round 7
// baseline (114.328 us; speedup 1.0000x reference)
//
#include <hip/hip_runtime.h>
#include <hip/hip_fp16.h>
#include <math.h>

#define N_PTS   8192
#define ENC     384
#define NTHREAD 384
#define NCELL1  8
#define NCELLS  512
#define RADIUS  0.12f
#define TILE    16
#define NTILES  (N_PTS / TILE)     // 512
#define MAXL    128                // per-point neighbor cap (mean 59, sigma 7.7)

__device__ __forceinline__ void fast_sincos(float x, float& s, float& c) {
    // gfx950 v_sin/v_cos take REVOLUTIONS. rev err <= |x|*2^-24 — negligible here.
    float rev = x * 0.15915494309189535f;
    rev -= rintf(rev);
    s = __builtin_amdgcn_sinf(rev);
    c = __builtin_amdgcn_cosf(rev);
}

__device__ __forceinline__ int cell_of(float x) {
    int c = (int)(x * 8.0f);
    return min(NCELL1 - 1, max(0, c));
}

// ---------------- ws layout (bytes) ----------------
static const size_t OFF_CSTART_I = 0;                        // 520 ints (513 used)
static const size_t OFF_SPTS_B   = 520 * 4;                  // 2080 (16B aligned)
static const size_t OFF_CS_B     = OFF_SPTS_B + (size_t)N_PTS * 16;   // 133152 (16B aligned)
// cs: (N_PTS+1) rows (ORIGINAL point order) x 384 half2; row 8192 = zero dummy
static const size_t WS_FULL_B    = OFF_CS_B + (size_t)(N_PTS + 1) * ENC * 4;  // ~12.7 MB

// ---------------- K1: count + scan + scatter, one block ----------------
__global__ __launch_bounds__(1024) void k_prep(const float* __restrict__ pts,
                                               int* __restrict__ cell_start_g,
                                               float4* __restrict__ spts) {
    __shared__ int cnt[NCELLS];
    __shared__ int sc[NCELLS];
    __shared__ int cur[NCELLS];
    const int t = threadIdx.x;
    if (t < NCELLS) cnt[t] = 0;
    __syncthreads();

    int   cids[8];
    float xs[8], ys[8], zs[8];
    #pragma unroll
    for (int k = 0; k < 8; ++k) {
        int i = t + k * 1024;
        float x = pts[3 * i + 0], y = pts[3 * i + 1], z = pts[3 * i + 2];
        xs[k] = x; ys[k] = y; zs[k] = z;
        int cid = (cell_of(x) << 6) | (cell_of(y) << 3) | cell_of(z);
        cids[k] = cid;
        atomicAdd(&cnt[cid], 1);
    }
    __syncthreads();
    if (t < NCELLS) sc[t] = cnt[t];
    __syncthreads();
    for (int off = 1; off < NCELLS; off <<= 1) {
        int v = 0;
        if (t < NCELLS && t >= off) v = sc[t - off];
        __syncthreads();
        if (t < NCELLS) sc[t] += v;
        __syncthreads();
    }
    if (t < NCELLS) {
        int excl = sc[t] - cnt[t];
        cell_start_g[t] = excl;
        cur[t] = excl;
    }
    if (t == 0) cell_start_g[NCELLS] = N_PTS;
    __syncthreads();
    #pragma unroll
    for (int k = 0; k < 8; ++k) {
        int i = t + k * 1024;
        int pos = atomicAdd(&cur[cids[k]], 1);
        spts[pos] = make_float4(xs[k], ys[k], zs[k], __int_as_float(i));
    }
}

// ---------------- K2: cs[orig_i][k] = (cos,sin) fp16, ORIGINAL order ----------------
__global__ __launch_bounds__(NTHREAD) void k_encode(const float* __restrict__ pts,
                                                    const float* __restrict__ A,
                                                    __half2* __restrict__ cs) {
    const int p = blockIdx.x;
    const int t = threadIdx.x;
    if (p == N_PTS) {                       // dummy zero row for padded lists
        cs[(size_t)p * ENC + t] = __floats2half2_rn(0.f, 0.f);
        return;
    }
    float qx = __fdiv_rn(pts[3 * p + 0], RADIUS);
    float qy = __fdiv_rn(pts[3 * p + 1], RADIUS);
    float qz = __fdiv_rn(pts[3 * p + 2], RADIUS);
    float a0 = A[t], a1 = A[ENC + t], a2 = A[2 * ENC + t];
    float pa = fmaf(qz, a2, fmaf(qy, a1, qx * a0));
    float s, c;
    fast_sincos(pa, s, c);
    cs[(size_t)p * ENC + t] = __floats2half2_rn(c, s);
}

// ---------------- K3: main — 16 points/block, per-point streams ----------------
__global__ __launch_bounds__(NTHREAD) void k_main(const float4* __restrict__ spts,
                                                  const int* __restrict__ cell_start,
                                                  const __half2* __restrict__ cs,
                                                  const float* __restrict__ A,
                                                  float* __restrict__ out, int out_mode) {
    // XCD-chunked swizzle: 64 consecutive tiles per XCD -> shared L2 window
    const int tile = (blockIdx.x & 7) * (NTILES / 8) + (blockIdx.x >> 3);
    const int t = threadIdx.x, lane = t & 63, wid = t >> 6;

    __shared__ float4 pts_l[TILE];
    __shared__ int    cid_l[TILE];
    __shared__ int    cnt16[TILE];
    __shared__ int    npad16[TILE];
    __shared__ __align__(16) unsigned short lists[TILE][MAXL];
    __shared__ float  redw[6][TILE];
    __shared__ float  scale_l[TILE];

    if (t < TILE) {
        float4 P = spts[tile * TILE + t];
        pts_l[t] = P;
        cnt16[t] = 0;
        cid_l[t] = (cell_of(P.x) << 6) | (cell_of(P.y) << 3) | cell_of(P.z);
    }
    __syncthreads();

    const double R2 = (double)0.12 * (double)0.12;
    const float R2_LO = 0.0144f - 1e-6f;
    const float R2_HI = 0.0144f + 1e-6f;
    const int p  = t & 15;      // point slot within pass
    const int cl = t >> 4;      // candidate slot 0..23

    // ---- Phase 1: per cell-run candidate scan (classification == R5/R6) ----
    int start = 0;
    while (start < TILE) {
        const int cid = cid_l[start];
        int end = start + 1;
        while (end < TILE && cid_l[end] == cid) ++end;
        const int len = end - start;

        const float4 Pi = pts_l[start + min(p, len - 1)];
        const float xi = Pi.x, yi = Pi.y, zi = Pi.z;
        const double dxi = (double)xi, dyi = (double)yi, dzi = (double)zi;

        const int cx = cid >> 6, cy = (cid >> 3) & 7, cz = cid & 7;
        const int zlo = max(cz - 1, 0), zhi = min(cz + 1, 7);

        for (int dx = -1; dx <= 1; ++dx) {
            int cxx = cx + dx;
            if (cxx < 0 || cxx > 7) continue;
            for (int dy = -1; dy <= 1; ++dy) {
                int cyy = cy + dy;
                if (cyy < 0 || cyy > 7) continue;
                int base = (cxx * 8 + cyy) * 8;
                int lo = cell_start[base + zlo];
                int hi = cell_start[base + zhi + 1];
                for (int jb = lo; jb < hi; jb += 24) {
                    int j = jb + cl;
                    bool isnb = false;
                    float4 Pj;
                    if (j < hi && p < len) {
                        Pj = spts[j];
                        float fdx = Pj.x - xi, fdy = Pj.y - yi, fdz = Pj.z - zi;
                        float d2f = fmaf(fdx, fdx, fmaf(fdy, fdy, fdz * fdz));
                        if (d2f < R2_LO) {
                            isnb = true;
                        } else if (d2f <= R2_HI) {
                            double ddx = (double)Pj.x - dxi, ddy = (double)Pj.y - dyi,
                                   ddz = (double)Pj.z - dzi;
                            isnb = (ddx * ddx + ddy * ddy + ddz * ddz) < R2;
                        }
                    }
                    if (isnb) {
                        int pos = atomicAdd(&cnt16[start + p], 1);
                        if (pos < MAXL)
                            lists[start + p][pos] = (unsigned short)__float_as_int(Pj.w);
                    }
                }
            }
        }
        start = end;
    }
    __syncthreads();
    if (t < TILE) {
        int c  = min(cnt16[t], MAXL);
        int cp = min((c + 7) & ~7, MAXL);
        for (int k = c; k < cp; ++k) lists[t][k] = (unsigned short)N_PTS;  // zero row
        npad16[t] = cp;
    }
    __syncthreads();

    // ---- Phase 2: per-point gather streams (static p -> registers) ----
    float gr[TILE], gi[TILE];
    #pragma unroll
    for (int q = 0; q < TILE; ++q) { gr[q] = 0.f; gi[q] = 0.f; }

    #pragma unroll
    for (int q = 0; q < TILE; ++q) {
        const int np = npad16[q];
        const unsigned short* lp = lists[q];
        for (int m = 0; m < np; m += 8) {
            uint4 iv = *reinterpret_cast<const uint4*>(lp + m);
            int j0 = (int)(iv.x & 0xFFFFu), j1 = (int)(iv.x >> 16);
            int j2 = (int)(iv.y & 0xFFFFu), j3 = (int)(iv.y >> 16);
            int j4 = (int)(iv.z & 0xFFFFu), j5 = (int)(iv.z >> 16);
            int j6 = (int)(iv.w & 0xFFFFu), j7 = (int)(iv.w >> 16);
            float2 f0 = __half22float2(cs[j0 * ENC + t]);
            float2 f1 = __half22float2(cs[j1 * ENC + t]);
            float2 f2 = __half22float2(cs[j2 * ENC + t]);
            float2 f3 = __half22float2(cs[j3 * ENC + t]);
            float2 f4 = __half22float2(cs[j4 * ENC + t]);
            float2 f5 = __half22float2(cs[j5 * ENC + t]);
            float2 f6 = __half22float2(cs[j6 * ENC + t]);
            float2 f7 = __half22float2(cs[j7 * ENC + t]);
            float sr = ((f0.x + f1.x) + (f2.x + f3.x)) + ((f4.x + f5.x) + (f6.x + f7.x));
            float si = ((f0.y + f1.y) + (f2.y + f3.y)) + ((f4.y + f5.y) + (f6.y + f7.y));
            gr[q] += sr;
            gi[q] += si;
        }
    }

    // ---- Phase 3: per-point norm (phase-invariant), rotate, scale, store ----
    #pragma unroll
    for (int q = 0; q < TILE; ++q) {
        float m2 = gr[q] * gr[q] + gi[q] * gi[q];
        #pragma unroll
        for (int off = 32; off > 0; off >>= 1) m2 += __shfl_down(m2, off);
        if (lane == 0) redw[wid][q] = m2;
    }
    __syncthreads();
    if (t < TILE) {
        float tot = redw[0][t] + redw[1][t] + redw[2][t]
                  + redw[3][t] + redw[4][t] + redw[5][t];
        scale_l[t] = sqrtf(384.0f / tot);
    }
    __syncthreads();

    const float a0 = A[t], a1 = A[ENC + t], a2 = A[2 * ENC + t];
    #pragma unroll
    for (int q = 0; q < TILE; ++q) {
        float4 P = pts_l[q];
        float qx = __fdiv_rn(P.x, RADIUS);
        float qy = __fdiv_rn(P.y, RADIUS);
        float qz = __fdiv_rn(P.z, RADIUS);
        float pa = fmaf(qz, a2, fmaf(qy, a1, qx * a0));
        float sv, cv;
        fast_sincos(pa, sv, cv);
        float sc = scale_l[q];
        float re = (gr[q] * cv + gi[q] * sv) * sc;
        float im = (gi[q] * cv - gr[q] * sv) * sc;
        int o = __float_as_int(P.w);
        if (out_mode == 0) {
            out[o * ENC + t] = re;
        } else {
            reinterpret_cast<float2*>(out)[o * ENC + t] = make_float2(re, im);
        }
    }
}

// ---------------- last-resort all-pairs (ws too small; effectively dead) ----------------
__global__ __launch_bounds__(NTHREAD) void vecKM_allpairs(const float* __restrict__ pts,
                                                          const float* __restrict__ A,
                                                          float* __restrict__ out, int out_mode) {
    const int i = blockIdx.x;
    const int t = threadIdx.x;
    __shared__ float nb_x[512], nb_y[512], nb_z[512];
    __shared__ int nb_cnt;
    __shared__ float red[8];
    if (t == 0) nb_cnt = 0;
    __syncthreads();
    const float xi = pts[3 * i + 0], yi = pts[3 * i + 1], zi = pts[3 * i + 2];
    const double dxi = xi, dyi = yi, dzi = zi;
    const double R2 = (double)0.12 * (double)0.12;
    const float R2_LO = 0.0144f - 1e-6f, R2_HI = 0.0144f + 1e-6f;
    const int lane = t & 63;
    for (int jb = 0; jb < N_PTS; jb += NTHREAD) {
        const int j = jb + t;
        bool isnb = false;
        float xj = 0.f, yj = 0.f, zj = 0.f;
        if (j < N_PTS) {
            xj = pts[3 * j + 0]; yj = pts[3 * j + 1]; zj = pts[3 * j + 2];
            float fdx = xj - xi, fdy = yj - yi, fdz = zj - zi;
            float d2f = fmaf(fdx, fdx, fmaf(fdy, fdy, fdz * fdz));
            if (d2f < R2_LO) isnb = true;
            else if (d2f <= R2_HI) {
                double dx = (double)xj - dxi, dy = (double)yj - dyi, dz = (double)zj - dzi;
                isnb = (dx * dx + dy * dy + dz * dz) < R2;
            }
        }
        unsigned long long mask = __ballot(isnb);
        if (mask) {
            int leader = __ffsll((long long)mask) - 1;
            int basep = 0;
            if (lane == leader) basep = atomicAdd(&nb_cnt, __popcll(mask));
            basep = __shfl(basep, leader);
            if (isnb) {
                int pos = basep + __popcll(mask & ((1ull << lane) - 1ull));
                if (pos < 512) {
                    nb_x[pos] = (xj - xi) * (1.0f / 0.12f);
                    nb_y[pos] = (yj - yi) * (1.0f / 0.12f);
                    nb_z[pos] = (zj - zi) * (1.0f / 0.12f);
                }
            }
        }
    }
    __syncthreads();
    const int nn = min(nb_cnt, 512);
    const float a0 = A[t], a1 = A[ENC + t], a2 = A[2 * ENC + t];
    float gr = 0.f, gi = 0.f;
    #pragma unroll 4
    for (int m = 0; m < nn; ++m) {
        float pa = fmaf(nb_z[m], a2, fmaf(nb_y[m], a1, nb_x[m] * a0));
        float sv, cv;
        fast_sincos(pa, sv, cv);
        gr += cv; gi += sv;
    }
    float m2 = fmaf(gr, gr, gi * gi);
    #pragma unroll
    for (int off = 32; off > 0; off >>= 1) m2 += __shfl_down(m2, off);
    const int wid = t >> 6;
    if (lane == 0) red[wid] = m2;
    __syncthreads();
    if (t == 0) {
        float tot = 0.f;
        for (int w = 0; w < NTHREAD / 64; ++w) tot += red[w];
        red[7] = tot;
    }
    __syncthreads();
    const float scale = sqrtf(384.0f / red[7]);
    const float re = gr * scale, im = gi * scale;
    if (out_mode == 0) out[i * ENC + t] = re;
    else ((float2*)out)[i * ENC + t] = make_float2(re, im);
}

extern "C" void kernel_launch(void* const* d_in, const int* in_sizes, int n_in,
                              void* d_out, int out_size, void* d_ws, size_t ws_size,
                              hipStream_t stream) {
    const float* pts = (const float*)d_in[0];
    const float* A   = (const float*)d_in[1];
    float* out = (float*)d_out;
    const int out_mode = (out_size >= 2 * N_PTS * ENC) ? 1 : 0;

    if (ws_size >= WS_FULL_B) {
        int*     cell_start = (int*)d_ws + OFF_CSTART_I;
        float4*  spts       = (float4*)((char*)d_ws + OFF_SPTS_B);
        __half2* cs         = (__half2*)((char*)d_ws + OFF_CS_B);

        k_prep<<<1, 1024, 0, stream>>>(pts, cell_start, spts);
        k_encode<<<N_PTS + 1, NTHREAD, 0, stream>>>(pts, A, cs);
        k_main<<<NTILES, NTHREAD, 0, stream>>>(spts, cell_start, cs, A, out, out_mode);
    } else {
        vecKM_allpairs<<<N_PTS, NTHREAD, 0, stream>>>(pts, A, out, out_mode);
    }
}